// Round 3
// 883.152 us; speedup vs baseline: 1.0604x; 1.0604x over previous
//
#include <hip/hip_runtime.h>
#include <cstddef>
#include <cstdint>

// Problem constants (B,T,D,H) = (64,512,2048,128)
#define BB 64
#define TT 512
#define DD 2048
#define HH 128
#define M1 (BB*TT)   // 32768 rows for gemm1

typedef __attribute__((ext_vector_type(8))) short bf16x8;
typedef __attribute__((ext_vector_type(4))) float f32x4;
typedef __attribute__((ext_vector_type(2))) _Float16 h2f;

__device__ __forceinline__ unsigned short f2bf(float f) {
    unsigned u = __builtin_bit_cast(unsigned, f);
    u += 0x7fffu + ((u >> 16) & 1u);          // RNE
    return (unsigned short)(u >> 16);
}
__device__ __forceinline__ float bf2f(unsigned short s) {
    return __builtin_bit_cast(float, ((unsigned)s) << 16);
}
__device__ __forceinline__ float tanh_fast(float x) {
    float e2x = __builtin_amdgcn_exp2f(x * 2.885390081777927f);
    return 1.0f - 2.0f * __builtin_amdgcn_rcpf(e2x + 1.0f);
}

// ---------------------------------------------------------------------------
// prep: split W_ih1 fp32 -> (hi, lo) bf16. hi = RNE(w); lo = RNE(w - hi).
// ---------------------------------------------------------------------------
__global__ __launch_bounds__(256) void prep_w_kernel(
    const float* __restrict__ W,
    unsigned short* __restrict__ Whi, unsigned short* __restrict__ Wlo)
{
    const int i = (blockIdx.x * 256 + threadIdx.x) * 4;
    float4 w = *(const float4*)(W + i);
    unsigned short h0 = f2bf(w.x), h1 = f2bf(w.y), h2 = f2bf(w.z), h3 = f2bf(w.w);
    unsigned short l0 = f2bf(w.x - bf2f(h0)), l1 = f2bf(w.y - bf2f(h1));
    unsigned short l2 = f2bf(w.z - bf2f(h2)), l3 = f2bf(w.w - bf2f(h3));
    ushort4 hv; hv.x = h0; hv.y = h1; hv.z = h2; hv.w = h3;
    ushort4 lv; lv.x = l0; lv.y = l1; lv.z = l2; lv.w = l3;
    *(ushort4*)(Whi + i) = hv;
    *(ushort4*)(Wlo + i) = lv;
}

// ---------------------------------------------------------------------------
// gemm1: out[m][n] = sum_k x[m][k]*W[n][k] + bia[n] + bib[n] via split-bf16
// MFMA 16x16x32. BM=64 (4 waves x 16 rows), N=128 (8 n-tiles/wave), BK=32.
// ---------------------------------------------------------------------------
__global__ __launch_bounds__(256) void gemm1_mfma_kernel(
    const float* __restrict__ A, const unsigned short* __restrict__ Whi,
    const unsigned short* __restrict__ Wlo,
    const float* __restrict__ bia, const float* __restrict__ bib,
    float* __restrict__ out)
{
    constexpr int K = DD, BK = 32, NK = K / BK;   // 64 iterations
    __shared__ __align__(16) short Ah[64 * 40];   // stride 40 -> 2-way banks max
    __shared__ __align__(16) short Al[64 * 40];
    __shared__ __align__(16) short Wh[128 * 40];
    __shared__ __align__(16) short Wl[128 * 40];

    const int tid = threadIdx.x, wave = tid >> 6, lane = tid & 63;
    const size_t m0 = (size_t)blockIdx.x * 64;
    const int ar = tid >> 2, ak = (tid & 3) * 8;      // A stage: row, k0
    const int wr = tid >> 1, wk = (tid & 1) * 16;     // W stage: row, k0
    const float* Ap = A + (m0 + ar) * (size_t)K + ak;
    const unsigned short* Whp = Whi + (size_t)wr * K + wk;
    const unsigned short* Wlp = Wlo + (size_t)wr * K + wk;
    const int frow = lane & 15, fko = (lane >> 4) * 8;

    f32x4 acc[8];
#pragma unroll
    for (int i = 0; i < 8; i++) acc[i] = (f32x4){0.f, 0.f, 0.f, 0.f};

    for (int kt = 0; kt < NK; ++kt) {
        float4 a0 = *(const float4*)(Ap + kt * BK);
        float4 a1 = *(const float4*)(Ap + kt * BK + 4);
        bf16x8 wh0 = *(const bf16x8*)(Whp + kt * BK);
        bf16x8 wh1 = *(const bf16x8*)(Whp + kt * BK + 8);
        bf16x8 wl0 = *(const bf16x8*)(Wlp + kt * BK);
        bf16x8 wl1 = *(const bf16x8*)(Wlp + kt * BK + 8);
        __syncthreads();   // previous iter's fragment reads complete
        float fv[8] = {a0.x, a0.y, a0.z, a0.w, a1.x, a1.y, a1.z, a1.w};
        unsigned short h[8], l[8];
#pragma unroll
        for (int i = 0; i < 8; i++) {
            h[i] = f2bf(fv[i]);
            l[i] = f2bf(fv[i] - bf2f(h[i]));
        }
        uint2 p0, p1, q0, q1;
        p0.x = (unsigned)h[0] | ((unsigned)h[1] << 16); p0.y = (unsigned)h[2] | ((unsigned)h[3] << 16);
        p1.x = (unsigned)h[4] | ((unsigned)h[5] << 16); p1.y = (unsigned)h[6] | ((unsigned)h[7] << 16);
        q0.x = (unsigned)l[0] | ((unsigned)l[1] << 16); q0.y = (unsigned)l[2] | ((unsigned)l[3] << 16);
        q1.x = (unsigned)l[4] | ((unsigned)l[5] << 16); q1.y = (unsigned)l[6] | ((unsigned)l[7] << 16);
        *(uint2*)&Ah[ar * 40 + ak]     = p0;
        *(uint2*)&Ah[ar * 40 + ak + 4] = p1;
        *(uint2*)&Al[ar * 40 + ak]     = q0;
        *(uint2*)&Al[ar * 40 + ak + 4] = q1;
        *(bf16x8*)&Wh[wr * 40 + wk]     = wh0;
        *(bf16x8*)&Wh[wr * 40 + wk + 8] = wh1;
        *(bf16x8*)&Wl[wr * 40 + wk]     = wl0;
        *(bf16x8*)&Wl[wr * 40 + wk + 8] = wl1;
        __syncthreads();
        bf16x8 fAh = *(const bf16x8*)&Ah[(wave * 16 + frow) * 40 + fko];
        bf16x8 fAl = *(const bf16x8*)&Al[(wave * 16 + frow) * 40 + fko];
#pragma unroll
        for (int nt = 0; nt < 8; ++nt) {
            bf16x8 fWh = *(const bf16x8*)&Wh[(nt * 16 + frow) * 40 + fko];
            bf16x8 fWl = *(const bf16x8*)&Wl[(nt * 16 + frow) * 40 + fko];
            acc[nt] = __builtin_amdgcn_mfma_f32_16x16x32_bf16(fAh, fWh, acc[nt], 0, 0, 0);
            acc[nt] = __builtin_amdgcn_mfma_f32_16x16x32_bf16(fAh, fWl, acc[nt], 0, 0, 0);
            acc[nt] = __builtin_amdgcn_mfma_f32_16x16x32_bf16(fAl, fWh, acc[nt], 0, 0, 0);
        }
    }
    const int rbase = (lane >> 4) * 4;
#pragma unroll
    for (int nt = 0; nt < 8; ++nt) {
        const int col = nt * 16 + frow;
        const float bv = bia[col] + bib[col];
#pragma unroll
        for (int r = 0; r < 4; r++)
            out[(m0 + wave * 16 + rbase + r) * HH + col] = acc[nt][r] + bv;
    }
}

// ---------------------------------------------------------------------------
// Fused scan (layer L) + optional on-the-fly pre-activation GEMM for layer
// L+1.  FOUR waves per batch element (256 thr), 64 blocks.
//
// Scan part (identical numerics to the passing v2):
//   lane owns output j = wave*32 + (lane&31) for K-half kh = lane>>5;
//   W_hh[j][kh*64..+63] in 32 packed-f16 VGPRs; 32 fdot2/step;
//   halves combined with one __shfl_xor(32); h published to double-buffered
//   LDS (f16); one __syncthreads per step; pre prefetched 2 steps ahead.
//
// Fused pre2 (iff FUSE_NEXT): after the barrier publishes h_t, the SAME
// lanes compute pre2[b][t][j] = sum_k h_t[k]*W_ih2[j][k] + bi2[j]+bh2[j]
// with 32 more fdot2 against W_ih2[j][kh*64..] held in 32 extra VGPRs;
// halves combined with one more __shfl_xor(32); kh==0 lanes store to
// global. This replaces the separate gemm2 kernel and removes the h1
// global round-trip entirely. hs[wb] (h_t) stays valid until step t+1's
// publish, which happens after the NEXT barrier — reads here are safe.
// ---------------------------------------------------------------------------
template<int FUSE_NEXT>
__global__ __launch_bounds__(256) void rnn_scan4_fused(
    const float* __restrict__ pre,   // [64][512][128] pre-activations, layer L
    const float* __restrict__ Whh,   // [128][128] fp32
    const float* __restrict__ Wih2,  // [128][128] fp32 (iff FUSE_NEXT)
    const float* __restrict__ bi2, const float* __restrict__ bh2,
    float* __restrict__ pre2,        // [64][512][128] out (iff FUSE_NEXT)
    const float* __restrict__ Wfc, const float* __restrict__ bfc,
    float* __restrict__ outv)        // [64] (iff !FUSE_NEXT)
{
    __shared__ __align__(16) _Float16 hs[2][HH];   // double buffer, 512 B
    __shared__ float red[4];
    const int tid  = threadIdx.x;
    const int wave = tid >> 6, lane = tid & 63;
    const int j  = wave * 32 + (lane & 31);   // output unit 0..127
    const int kh = lane >> 5;                 // 0/1: which K half this lane does
    const int b  = blockIdx.x;

    // W_hh[j][kh*64 .. +63] -> 32 packed f16 pairs in VGPRs
    h2f Wr[32];
    {
        const float* r = Whh + (size_t)j * HH + kh * 64;
#pragma unroll
        for (int q = 0; q < 16; q++) {
            float4 w = *(const float4*)(r + q * 4);
            Wr[2 * q]     = h2f{(_Float16)w.x, (_Float16)w.y};
            Wr[2 * q + 1] = h2f{(_Float16)w.z, (_Float16)w.w};
        }
    }
    // W_ih2[j][kh*64 .. +63] likewise (only if fusing the next layer's GEMM)
    h2f W2r[32];
    float bias2 = 0.f;
    if (FUSE_NEXT) {
        const float* r = Wih2 + (size_t)j * HH + kh * 64;
#pragma unroll
        for (int q = 0; q < 16; q++) {
            float4 w = *(const float4*)(r + q * 4);
            W2r[2 * q]     = h2f{(_Float16)w.x, (_Float16)w.y};
            W2r[2 * q + 1] = h2f{(_Float16)w.z, (_Float16)w.w};
        }
        bias2 = bi2[j] + bh2[j];
    }
    if (tid < HH) hs[0][tid] = (_Float16)0.f;

    const float* pb = pre + (size_t)b * TT * HH;
    float* p2b = FUSE_NEXT ? (pre2 + (size_t)b * TT * HH) : nullptr;
    // 2-deep prefetch of pre: covers HBM-miss latency (~900cy > 1 step)
    float pn0 = pb[j];
    float pn1 = pb[(size_t)HH + j];
    float fcv = 0.f;
    __syncthreads();

    for (int t = 0; t < TT; ++t) {
        const float p = pn0;
        pn0 = pn1;
        if (t + 2 < TT) pn1 = pb[(size_t)(t + 2) * HH + j];
        const int rb = t & 1;        // read h_{t-1} from hs[rb]
        const int wb = rb ^ 1;       // write h_t to hs[wb]
        const _Float16* hp = &hs[rb][kh * 64];
        float a0 = 0.f, a1 = 0.f, a2 = 0.f, a3 = 0.f;
#pragma unroll
        for (int q = 0; q < 8; q++) {
            uint4 hv = *(const uint4*)(hp + q * 8);   // broadcast read
            h2f x0 = __builtin_bit_cast(h2f, hv.x);
            h2f x1 = __builtin_bit_cast(h2f, hv.y);
            h2f x2 = __builtin_bit_cast(h2f, hv.z);
            h2f x3 = __builtin_bit_cast(h2f, hv.w);
            a0 = __builtin_amdgcn_fdot2(Wr[4 * q],     x0, a0, false);
            a1 = __builtin_amdgcn_fdot2(Wr[4 * q + 1], x1, a1, false);
            a2 = __builtin_amdgcn_fdot2(Wr[4 * q + 2], x2, a2, false);
            a3 = __builtin_amdgcn_fdot2(Wr[4 * q + 3], x3, a3, false);
        }
        float s = (a0 + a1) + (a2 + a3);
        s += __shfl_xor(s, 32);          // combine the two K-halves
        const float h = tanh_fast(p + s);
        if (lane < 32) hs[wb][j] = (_Float16)h;   // publish h_t (f16)
        if (!FUSE_NEXT && t == TT - 1 && lane < 32) fcv = h * Wfc[j];
        __syncthreads();                 // h_t visible to all waves

        if (FUSE_NEXT) {
            const _Float16* h2p = &hs[wb][kh * 64];
            float c0 = 0.f, c1 = 0.f, c2 = 0.f, c3 = 0.f;
#pragma unroll
            for (int q = 0; q < 8; q++) {
                uint4 hv = *(const uint4*)(h2p + q * 8);
                h2f x0 = __builtin_bit_cast(h2f, hv.x);
                h2f x1 = __builtin_bit_cast(h2f, hv.y);
                h2f x2 = __builtin_bit_cast(h2f, hv.z);
                h2f x3 = __builtin_bit_cast(h2f, hv.w);
                c0 = __builtin_amdgcn_fdot2(W2r[4 * q],     x0, c0, false);
                c1 = __builtin_amdgcn_fdot2(W2r[4 * q + 1], x1, c1, false);
                c2 = __builtin_amdgcn_fdot2(W2r[4 * q + 2], x2, c2, false);
                c3 = __builtin_amdgcn_fdot2(W2r[4 * q + 3], x3, c3, false);
            }
            float s2 = (c0 + c1) + (c2 + c3);
            s2 += __shfl_xor(s2, 32);
            if (lane < 32) p2b[(size_t)t * HH + j] = s2 + bias2;
        }
    }

    if (!FUSE_NEXT) {
#pragma unroll
        for (int off = 1; off < 64; off <<= 1) fcv += __shfl_xor(fcv, off);
        if (lane == 0) red[wave] = fcv;
        __syncthreads();
        if (tid == 0) outv[b] = red[0] + red[1] + red[2] + red[3] + bfc[0];
    }
}

// ---------------------------------------------------------------------------
extern "C" void kernel_launch(void* const* d_in, const int* in_sizes, int n_in,
                              void* d_out, int out_size, void* d_ws, size_t ws_size,
                              hipStream_t stream) {
    const float* x    = (const float*)d_in[0];
    const float* Wih1 = (const float*)d_in[1];
    const float* Whh1 = (const float*)d_in[2];
    const float* bih1 = (const float*)d_in[3];
    const float* bhh1 = (const float*)d_in[4];
    const float* Wih2 = (const float*)d_in[5];
    const float* Whh2 = (const float*)d_in[6];
    const float* bih2 = (const float*)d_in[7];
    const float* bhh2 = (const float*)d_in[8];
    const float* Wfc  = (const float*)d_in[9];
    const float* bfc  = (const float*)d_in[10];
    float* out = (float*)d_out;

    float* preA = (float*)d_ws;                    // 16 MB  (pre1)
    float* preB = preA + (size_t)M1 * HH;          // 16 MB  (pre2)
    // Whi/Wlo alias the head of preB: consumed by gemm1 BEFORE scan1 writes preB
    unsigned short* Whi = (unsigned short*)preB;
    unsigned short* Wlo = Whi + (size_t)HH * DD;

    prep_w_kernel<<<dim3(HH * DD / 1024), dim3(256), 0, stream>>>(Wih1, Whi, Wlo);
    gemm1_mfma_kernel<<<dim3(M1 / 64), dim3(256), 0, stream>>>(x, Whi, Wlo, bih1, bhh1, preA);
    // scan layer 1, fused with pre2 = h1 @ W_ih2^T + b  (gemm2 eliminated)
    rnn_scan4_fused<1><<<dim3(BB), dim3(256), 0, stream>>>(
        preA, Whh1, Wih2, bih2, bhh2, preB, Wfc, bfc, out);
    // scan layer 2 + FC head
    rnn_scan4_fused<0><<<dim3(BB), dim3(256), 0, stream>>>(
        preB, Whh2, nullptr, nullptr, nullptr, nullptr, Wfc, bfc, out);
}

// Round 5
// 882.799 us; speedup vs baseline: 1.0608x; 1.0004x over previous
//
#include <hip/hip_runtime.h>
#include <cstddef>
#include <cstdint>

// Problem constants (B,T,D,H) = (64,512,2048,128)
#define BB 64
#define TT 512
#define DD 2048
#define HH 128
#define M1 (BB*TT)   // 32768 rows for gemm1

typedef __attribute__((ext_vector_type(8))) short bf16x8;
typedef __attribute__((ext_vector_type(4))) float f32x4;
typedef __attribute__((ext_vector_type(2))) _Float16 h2f;

__device__ __forceinline__ unsigned short f2bf(float f) {
    unsigned u = __builtin_bit_cast(unsigned, f);
    u += 0x7fffu + ((u >> 16) & 1u);          // RNE
    return (unsigned short)(u >> 16);
}
__device__ __forceinline__ float bf2f(unsigned short s) {
    return __builtin_bit_cast(float, ((unsigned)s) << 16);
}
__device__ __forceinline__ float tanh_fast(float x) {
    float e2x = __builtin_amdgcn_exp2f(x * 2.885390081777927f);
    return 1.0f - 2.0f * __builtin_amdgcn_rcpf(e2x + 1.0f);
}

// ---------------------------------------------------------------------------
// prep: split W_ih1 fp32 -> (hi, lo) bf16. hi = RNE(w); lo = RNE(w - hi).
// ---------------------------------------------------------------------------
__global__ __launch_bounds__(256) void prep_w_kernel(
    const float* __restrict__ W,
    unsigned short* __restrict__ Whi, unsigned short* __restrict__ Wlo)
{
    const int i = (blockIdx.x * 256 + threadIdx.x) * 4;
    float4 w = *(const float4*)(W + i);
    unsigned short h0 = f2bf(w.x), h1 = f2bf(w.y), h2 = f2bf(w.z), h3 = f2bf(w.w);
    unsigned short l0 = f2bf(w.x - bf2f(h0)), l1 = f2bf(w.y - bf2f(h1));
    unsigned short l2 = f2bf(w.z - bf2f(h2)), l3 = f2bf(w.w - bf2f(h3));
    ushort4 hv; hv.x = h0; hv.y = h1; hv.z = h2; hv.w = h3;
    ushort4 lv; lv.x = l0; lv.y = l1; lv.z = l2; lv.w = l3;
    *(ushort4*)(Whi + i) = hv;
    *(ushort4*)(Wlo + i) = lv;
}

// ---------------------------------------------------------------------------
// gemm1: out[m][n] = sum_k x[m][k]*W[n][k] + bia[n] + bib[n] via split-bf16
// MFMA 16x16x32. BM=64 (4 waves x 16 rows), N=128 (8 n-tiles/wave), BK=32.
// ---------------------------------------------------------------------------
__global__ __launch_bounds__(256) void gemm1_mfma_kernel(
    const float* __restrict__ A, const unsigned short* __restrict__ Whi,
    const unsigned short* __restrict__ Wlo,
    const float* __restrict__ bia, const float* __restrict__ bib,
    float* __restrict__ out)
{
    constexpr int K = DD, BK = 32, NK = K / BK;   // 64 iterations
    __shared__ __align__(16) short Ah[64 * 40];   // stride 40 -> 2-way banks max
    __shared__ __align__(16) short Al[64 * 40];
    __shared__ __align__(16) short Wh[128 * 40];
    __shared__ __align__(16) short Wl[128 * 40];

    const int tid = threadIdx.x, wave = tid >> 6, lane = tid & 63;
    const size_t m0 = (size_t)blockIdx.x * 64;
    const int ar = tid >> 2, ak = (tid & 3) * 8;      // A stage: row, k0
    const int wr = tid >> 1, wk = (tid & 1) * 16;     // W stage: row, k0
    const float* Ap = A + (m0 + ar) * (size_t)K + ak;
    const unsigned short* Whp = Whi + (size_t)wr * K + wk;
    const unsigned short* Wlp = Wlo + (size_t)wr * K + wk;
    const int frow = lane & 15, fko = (lane >> 4) * 8;

    f32x4 acc[8];
#pragma unroll
    for (int i = 0; i < 8; i++) acc[i] = (f32x4){0.f, 0.f, 0.f, 0.f};

    for (int kt = 0; kt < NK; ++kt) {
        float4 a0 = *(const float4*)(Ap + kt * BK);
        float4 a1 = *(const float4*)(Ap + kt * BK + 4);
        bf16x8 wh0 = *(const bf16x8*)(Whp + kt * BK);
        bf16x8 wh1 = *(const bf16x8*)(Whp + kt * BK + 8);
        bf16x8 wl0 = *(const bf16x8*)(Wlp + kt * BK);
        bf16x8 wl1 = *(const bf16x8*)(Wlp + kt * BK + 8);
        __syncthreads();   // previous iter's fragment reads complete
        float fv[8] = {a0.x, a0.y, a0.z, a0.w, a1.x, a1.y, a1.z, a1.w};
        unsigned short h[8], l[8];
#pragma unroll
        for (int i = 0; i < 8; i++) {
            h[i] = f2bf(fv[i]);
            l[i] = f2bf(fv[i] - bf2f(h[i]));
        }
        uint2 p0, p1, q0, q1;
        p0.x = (unsigned)h[0] | ((unsigned)h[1] << 16); p0.y = (unsigned)h[2] | ((unsigned)h[3] << 16);
        p1.x = (unsigned)h[4] | ((unsigned)h[5] << 16); p1.y = (unsigned)h[6] | ((unsigned)h[7] << 16);
        q0.x = (unsigned)l[0] | ((unsigned)l[1] << 16); q0.y = (unsigned)l[2] | ((unsigned)l[3] << 16);
        q1.x = (unsigned)l[4] | ((unsigned)l[5] << 16); q1.y = (unsigned)l[6] | ((unsigned)l[7] << 16);
        *(uint2*)&Ah[ar * 40 + ak]     = p0;
        *(uint2*)&Ah[ar * 40 + ak + 4] = p1;
        *(uint2*)&Al[ar * 40 + ak]     = q0;
        *(uint2*)&Al[ar * 40 + ak + 4] = q1;
        *(bf16x8*)&Wh[wr * 40 + wk]     = wh0;
        *(bf16x8*)&Wh[wr * 40 + wk + 8] = wh1;
        *(bf16x8*)&Wl[wr * 40 + wk]     = wl0;
        *(bf16x8*)&Wl[wr * 40 + wk + 8] = wl1;
        __syncthreads();
        bf16x8 fAh = *(const bf16x8*)&Ah[(wave * 16 + frow) * 40 + fko];
        bf16x8 fAl = *(const bf16x8*)&Al[(wave * 16 + frow) * 40 + fko];
#pragma unroll
        for (int nt = 0; nt < 8; ++nt) {
            bf16x8 fWh = *(const bf16x8*)&Wh[(nt * 16 + frow) * 40 + fko];
            bf16x8 fWl = *(const bf16x8*)&Wl[(nt * 16 + frow) * 40 + fko];
            acc[nt] = __builtin_amdgcn_mfma_f32_16x16x32_bf16(fAh, fWh, acc[nt], 0, 0, 0);
            acc[nt] = __builtin_amdgcn_mfma_f32_16x16x32_bf16(fAh, fWl, acc[nt], 0, 0, 0);
            acc[nt] = __builtin_amdgcn_mfma_f32_16x16x32_bf16(fAl, fWh, acc[nt], 0, 0, 0);
        }
    }
    const int rbase = (lane >> 4) * 4;
#pragma unroll
    for (int nt = 0; nt < 8; ++nt) {
        const int col = nt * 16 + frow;
        const float bv = bia[col] + bib[col];
#pragma unroll
        for (int r = 0; r < 4; r++)
            out[(m0 + wave * 16 + rbase + r) * HH + col] = acc[nt][r] + bv;
    }
}

// ---------------------------------------------------------------------------
// Scan layer 1 FUSED with pre2 = h1 @ W_ih2^T + b.  4 waves / batch elem.
// __launch_bounds__(256, 1): min 1 wave/EU -> full VGPR budget available;
// prevents the allocator from spilling the 64 packed-f16 weight regs
// (R3 post-mortem: spill to scratch cost 3x). Non-template function so
// regalloc is independent of the final-scan kernel (rule #19).
// ---------------------------------------------------------------------------
__global__ __launch_bounds__(256, 1) void rnn_scan4_fused1(
    const float* __restrict__ pre,   // [64][512][128] pre-activations layer 1
    const float* __restrict__ Whh,   // [128][128] fp32
    const float* __restrict__ Wih2,  // [128][128] fp32
    const float* __restrict__ bi2, const float* __restrict__ bh2,
    float* __restrict__ pre2)        // [64][512][128] out
{
    __shared__ __align__(16) _Float16 hs[2][HH];   // double buffer, 512 B
    const int tid  = threadIdx.x;
    const int wave = tid >> 6, lane = tid & 63;
    const int j  = wave * 32 + (lane & 31);   // output unit 0..127
    const int kh = lane >> 5;                 // 0/1: which K half this lane does
    const int b  = blockIdx.x;

    h2f Wr[32];    // W_hh[j][kh*64 .. +63]
    h2f W2r[32];   // W_ih2[j][kh*64 .. +63]
    {
        const float* r = Whh + (size_t)j * HH + kh * 64;
        const float* r2 = Wih2 + (size_t)j * HH + kh * 64;
#pragma unroll
        for (int q = 0; q < 16; q++) {
            float4 w = *(const float4*)(r + q * 4);
            Wr[2 * q]     = h2f{(_Float16)w.x, (_Float16)w.y};
            Wr[2 * q + 1] = h2f{(_Float16)w.z, (_Float16)w.w};
            float4 v = *(const float4*)(r2 + q * 4);
            W2r[2 * q]     = h2f{(_Float16)v.x, (_Float16)v.y};
            W2r[2 * q + 1] = h2f{(_Float16)v.z, (_Float16)v.w};
        }
    }
    const float bias2 = bi2[j] + bh2[j];
    if (tid < HH) hs[0][tid] = (_Float16)0.f;

    const float* pb = pre + (size_t)b * TT * HH;
    float* p2b = pre2 + (size_t)b * TT * HH;
    float pn0 = pb[j];                 // 2-deep pre prefetch
    float pn1 = pb[(size_t)HH + j];
    __syncthreads();

    for (int t = 0; t < TT; ++t) {
        const float p = pn0;
        pn0 = pn1;
        if (t + 2 < TT) pn1 = pb[(size_t)(t + 2) * HH + j];
        const int rb = t & 1;
        const int wb = rb ^ 1;
        const _Float16* hp = &hs[rb][kh * 64];
        float a0 = 0.f, a1 = 0.f, a2 = 0.f, a3 = 0.f;
#pragma unroll
        for (int q = 0; q < 8; q++) {
            uint4 hv = *(const uint4*)(hp + q * 8);   // broadcast read
            h2f x0 = __builtin_bit_cast(h2f, hv.x);
            h2f x1 = __builtin_bit_cast(h2f, hv.y);
            h2f x2 = __builtin_bit_cast(h2f, hv.z);
            h2f x3 = __builtin_bit_cast(h2f, hv.w);
            a0 = __builtin_amdgcn_fdot2(Wr[4 * q],     x0, a0, false);
            a1 = __builtin_amdgcn_fdot2(Wr[4 * q + 1], x1, a1, false);
            a2 = __builtin_amdgcn_fdot2(Wr[4 * q + 2], x2, a2, false);
            a3 = __builtin_amdgcn_fdot2(Wr[4 * q + 3], x3, a3, false);
        }
        float s = (a0 + a1) + (a2 + a3);
        s += __shfl_xor(s, 32);          // combine the two K-halves
        const float h = tanh_fast(p + s);
        if (lane < 32) hs[wb][j] = (_Float16)h;   // publish h_t (f16)
        __syncthreads();                 // h_t visible to all waves

        // pre2[b][t][j] = h_t . W_ih2[j] + bias2  (reads hs[wb] = h_t; safe
        // until step t+1's publish, which is after the NEXT barrier)
        const _Float16* h2p = &hs[wb][kh * 64];
        float c0 = 0.f, c1 = 0.f, c2 = 0.f, c3 = 0.f;
#pragma unroll
        for (int q = 0; q < 8; q++) {
            uint4 hv = *(const uint4*)(h2p + q * 8);
            h2f x0 = __builtin_bit_cast(h2f, hv.x);
            h2f x1 = __builtin_bit_cast(h2f, hv.y);
            h2f x2 = __builtin_bit_cast(h2f, hv.z);
            h2f x3 = __builtin_bit_cast(h2f, hv.w);
            c0 = __builtin_amdgcn_fdot2(W2r[4 * q],     x0, c0, false);
            c1 = __builtin_amdgcn_fdot2(W2r[4 * q + 1], x1, c1, false);
            c2 = __builtin_amdgcn_fdot2(W2r[4 * q + 2], x2, c2, false);
            c3 = __builtin_amdgcn_fdot2(W2r[4 * q + 3], x3, c3, false);
        }
        float s2 = (c0 + c1) + (c2 + c3);
        s2 += __shfl_xor(s2, 32);
        if (lane < 32) p2b[(size_t)t * HH + j] = s2 + bias2;
    }
}

// ---------------------------------------------------------------------------
// Scan layer 2 + FC head (identical to R1's passing kernel + 2-deep prefetch)
// ---------------------------------------------------------------------------
__global__ __launch_bounds__(256, 1) void rnn_scan4_final(
    const float* __restrict__ pre,   // [64][512][128] pre-activations layer 2
    const float* __restrict__ Whh,   // [128][128] fp32
    const float* __restrict__ Wfc, const float* __restrict__ bfc,
    float* __restrict__ outv)        // [64]
{
    __shared__ __align__(16) _Float16 hs[2][HH];
    __shared__ float red[4];
    const int tid  = threadIdx.x;
    const int wave = tid >> 6, lane = tid & 63;
    const int j  = wave * 32 + (lane & 31);
    const int kh = lane >> 5;
    const int b  = blockIdx.x;

    h2f Wr[32];
    {
        const float* r = Whh + (size_t)j * HH + kh * 64;
#pragma unroll
        for (int q = 0; q < 16; q++) {
            float4 w = *(const float4*)(r + q * 4);
            Wr[2 * q]     = h2f{(_Float16)w.x, (_Float16)w.y};
            Wr[2 * q + 1] = h2f{(_Float16)w.z, (_Float16)w.w};
        }
    }
    if (tid < HH) hs[0][tid] = (_Float16)0.f;

    const float* pb = pre + (size_t)b * TT * HH;
    float pn0 = pb[j];
    float pn1 = pb[(size_t)HH + j];
    float fcv = 0.f;
    __syncthreads();

    for (int t = 0; t < TT; ++t) {
        const float p = pn0;
        pn0 = pn1;
        if (t + 2 < TT) pn1 = pb[(size_t)(t + 2) * HH + j];
        const int rb = t & 1;
        const int wb = rb ^ 1;
        const _Float16* hp = &hs[rb][kh * 64];
        float a0 = 0.f, a1 = 0.f, a2 = 0.f, a3 = 0.f;
#pragma unroll
        for (int q = 0; q < 8; q++) {
            uint4 hv = *(const uint4*)(hp + q * 8);
            h2f x0 = __builtin_bit_cast(h2f, hv.x);
            h2f x1 = __builtin_bit_cast(h2f, hv.y);
            h2f x2 = __builtin_bit_cast(h2f, hv.z);
            h2f x3 = __builtin_bit_cast(h2f, hv.w);
            a0 = __builtin_amdgcn_fdot2(Wr[4 * q],     x0, a0, false);
            a1 = __builtin_amdgcn_fdot2(Wr[4 * q + 1], x1, a1, false);
            a2 = __builtin_amdgcn_fdot2(Wr[4 * q + 2], x2, a2, false);
            a3 = __builtin_amdgcn_fdot2(Wr[4 * q + 3], x3, a3, false);
        }
        float s = (a0 + a1) + (a2 + a3);
        s += __shfl_xor(s, 32);
        const float h = tanh_fast(p + s);
        if (lane < 32) hs[wb][j] = (_Float16)h;
        if (t == TT - 1 && lane < 32) fcv = h * Wfc[j];
        __syncthreads();
    }

#pragma unroll
    for (int off = 1; off < 64; off <<= 1) fcv += __shfl_xor(fcv, off);
    if (lane == 0) red[wave] = fcv;
    __syncthreads();
    if (tid == 0) outv[b] = red[0] + red[1] + red[2] + red[3] + bfc[0];
}

// ---------------------------------------------------------------------------
extern "C" void kernel_launch(void* const* d_in, const int* in_sizes, int n_in,
                              void* d_out, int out_size, void* d_ws, size_t ws_size,
                              hipStream_t stream) {
    const float* x    = (const float*)d_in[0];
    const float* Wih1 = (const float*)d_in[1];
    const float* Whh1 = (const float*)d_in[2];
    const float* bih1 = (const float*)d_in[3];
    const float* bhh1 = (const float*)d_in[4];
    const float* Wih2 = (const float*)d_in[5];
    const float* Whh2 = (const float*)d_in[6];
    const float* bih2 = (const float*)d_in[7];
    const float* bhh2 = (const float*)d_in[8];
    const float* Wfc  = (const float*)d_in[9];
    const float* bfc  = (const float*)d_in[10];
    float* out = (float*)d_out;

    float* preA = (float*)d_ws;                    // 16 MB  (pre1)
    float* preB = preA + (size_t)M1 * HH;          // 16 MB  (pre2)
    // Whi/Wlo alias the head of preB: consumed by gemm1 BEFORE scan1 writes preB
    unsigned short* Whi = (unsigned short*)preB;
    unsigned short* Wlo = Whi + (size_t)HH * DD;

    prep_w_kernel<<<dim3(HH * DD / 1024), dim3(256), 0, stream>>>(Wih1, Whi, Wlo);
    gemm1_mfma_kernel<<<dim3(M1 / 64), dim3(256), 0, stream>>>(x, Whi, Wlo, bih1, bhh1, preA);
    rnn_scan4_fused1<<<dim3(BB), dim3(256), 0, stream>>>(
        preA, Whh1, Wih2, bih2, bhh2, preB);
    rnn_scan4_final<<<dim3(BB), dim3(256), 0, stream>>>(
        preB, Whh2, Wfc, bfc, out);
}

// Round 6
// 761.955 us; speedup vs baseline: 1.2290x; 1.1586x over previous
//
#include <hip/hip_runtime.h>
#include <cstddef>
#include <cstdint>

// Problem constants (B,T,D,H) = (64,512,2048,128)
#define BB 64
#define TT 512
#define DD 2048
#define HH 128
#define M1 (BB*TT)   // 32768 rows for gemm1

typedef __attribute__((ext_vector_type(8))) short bf16x8;
typedef __attribute__((ext_vector_type(4))) float f32x4;
typedef __attribute__((ext_vector_type(2))) _Float16 h2f;

__device__ __forceinline__ unsigned short f2bf(float f) {
    unsigned u = __builtin_bit_cast(unsigned, f);
    u += 0x7fffu + ((u >> 16) & 1u);          // RNE
    return (unsigned short)(u >> 16);
}
__device__ __forceinline__ float bf2f(unsigned short s) {
    return __builtin_bit_cast(float, ((unsigned)s) << 16);
}
__device__ __forceinline__ float tanh_fast(float x) {
    float e2x = __builtin_amdgcn_exp2f(x * 2.885390081777927f);
    return 1.0f - 2.0f * __builtin_amdgcn_rcpf(e2x + 1.0f);
}

// 64-length f16 dot: 32 fdot2 of Wr[] against LDS h at hp, 4 accum chains.
__device__ __forceinline__ float dot64_f16(const h2f* Wr, const _Float16* hp) {
    float a0 = 0.f, a1 = 0.f, a2 = 0.f, a3 = 0.f;
#pragma unroll
    for (int q = 0; q < 8; q++) {
        uint4 hv = *(const uint4*)(hp + q * 8);   // broadcast read
        h2f x0 = __builtin_bit_cast(h2f, hv.x);
        h2f x1 = __builtin_bit_cast(h2f, hv.y);
        h2f x2 = __builtin_bit_cast(h2f, hv.z);
        h2f x3 = __builtin_bit_cast(h2f, hv.w);
        a0 = __builtin_amdgcn_fdot2(Wr[4 * q],     x0, a0, false);
        a1 = __builtin_amdgcn_fdot2(Wr[4 * q + 1], x1, a1, false);
        a2 = __builtin_amdgcn_fdot2(Wr[4 * q + 2], x2, a2, false);
        a3 = __builtin_amdgcn_fdot2(Wr[4 * q + 3], x3, a3, false);
    }
    return (a0 + a1) + (a2 + a3);
}

// Load 64 fp32 weights at r as 32 packed-f16 VGPRs, then pin them with a
// keep-alive asm: the values become asm outputs, so the allocator cannot
// rematerialize the loads inside the time loop (R5 post-mortem: remat of
// the weight loads per step was the 3x regression).
__device__ __forceinline__ void load_w32(h2f* Wr, const float* r) {
#pragma unroll
    for (int q = 0; q < 16; q++) {
        float4 w = *(const float4*)(r + q * 4);
        Wr[2 * q]     = h2f{(_Float16)w.x, (_Float16)w.y};
        Wr[2 * q + 1] = h2f{(_Float16)w.z, (_Float16)w.w};
    }
#pragma unroll
    for (int i = 0; i < 32; i++) {
        unsigned u = __builtin_bit_cast(unsigned, Wr[i]);
        asm volatile("" : "+v"(u));
        Wr[i] = __builtin_bit_cast(h2f, u);
    }
}

// ---------------------------------------------------------------------------
// prep: split W_ih1 fp32 -> (hi, lo) bf16. hi = RNE(w); lo = RNE(w - hi).
// ---------------------------------------------------------------------------
__global__ __launch_bounds__(256) void prep_w_kernel(
    const float* __restrict__ W,
    unsigned short* __restrict__ Whi, unsigned short* __restrict__ Wlo)
{
    const int i = (blockIdx.x * 256 + threadIdx.x) * 4;
    float4 w = *(const float4*)(W + i);
    unsigned short h0 = f2bf(w.x), h1 = f2bf(w.y), h2 = f2bf(w.z), h3 = f2bf(w.w);
    unsigned short l0 = f2bf(w.x - bf2f(h0)), l1 = f2bf(w.y - bf2f(h1));
    unsigned short l2 = f2bf(w.z - bf2f(h2)), l3 = f2bf(w.w - bf2f(h3));
    ushort4 hv; hv.x = h0; hv.y = h1; hv.z = h2; hv.w = h3;
    ushort4 lv; lv.x = l0; lv.y = l1; lv.z = l2; lv.w = l3;
    *(ushort4*)(Whi + i) = hv;
    *(ushort4*)(Wlo + i) = lv;
}

// ---------------------------------------------------------------------------
// gemm1: out[m][n] = sum_k x[m][k]*W[n][k] + bia[n] + bib[n] via split-bf16
// MFMA 16x16x32. BM=64 (4 waves x 16 rows), N=128 (8 n-tiles/wave), BK=32.
// ---------------------------------------------------------------------------
__global__ __launch_bounds__(256) void gemm1_mfma_kernel(
    const float* __restrict__ A, const unsigned short* __restrict__ Whi,
    const unsigned short* __restrict__ Wlo,
    const float* __restrict__ bia, const float* __restrict__ bib,
    float* __restrict__ out)
{
    constexpr int K = DD, BK = 32, NK = K / BK;   // 64 iterations
    __shared__ __align__(16) short Ah[64 * 40];   // stride 40 -> 2-way banks max
    __shared__ __align__(16) short Al[64 * 40];
    __shared__ __align__(16) short Wh[128 * 40];
    __shared__ __align__(16) short Wl[128 * 40];

    const int tid = threadIdx.x, wave = tid >> 6, lane = tid & 63;
    const size_t m0 = (size_t)blockIdx.x * 64;
    const int ar = tid >> 2, ak = (tid & 3) * 8;      // A stage: row, k0
    const int wr = tid >> 1, wk = (tid & 1) * 16;     // W stage: row, k0
    const float* Ap = A + (m0 + ar) * (size_t)K + ak;
    const unsigned short* Whp = Whi + (size_t)wr * K + wk;
    const unsigned short* Wlp = Wlo + (size_t)wr * K + wk;
    const int frow = lane & 15, fko = (lane >> 4) * 8;

    f32x4 acc[8];
#pragma unroll
    for (int i = 0; i < 8; i++) acc[i] = (f32x4){0.f, 0.f, 0.f, 0.f};

    for (int kt = 0; kt < NK; ++kt) {
        float4 a0 = *(const float4*)(Ap + kt * BK);
        float4 a1 = *(const float4*)(Ap + kt * BK + 4);
        bf16x8 wh0 = *(const bf16x8*)(Whp + kt * BK);
        bf16x8 wh1 = *(const bf16x8*)(Whp + kt * BK + 8);
        bf16x8 wl0 = *(const bf16x8*)(Wlp + kt * BK);
        bf16x8 wl1 = *(const bf16x8*)(Wlp + kt * BK + 8);
        __syncthreads();   // previous iter's fragment reads complete
        float fv[8] = {a0.x, a0.y, a0.z, a0.w, a1.x, a1.y, a1.z, a1.w};
        unsigned short h[8], l[8];
#pragma unroll
        for (int i = 0; i < 8; i++) {
            h[i] = f2bf(fv[i]);
            l[i] = f2bf(fv[i] - bf2f(h[i]));
        }
        uint2 p0, p1, q0, q1;
        p0.x = (unsigned)h[0] | ((unsigned)h[1] << 16); p0.y = (unsigned)h[2] | ((unsigned)h[3] << 16);
        p1.x = (unsigned)h[4] | ((unsigned)h[5] << 16); p1.y = (unsigned)h[6] | ((unsigned)h[7] << 16);
        q0.x = (unsigned)l[0] | ((unsigned)l[1] << 16); q0.y = (unsigned)l[2] | ((unsigned)l[3] << 16);
        q1.x = (unsigned)l[4] | ((unsigned)l[5] << 16); q1.y = (unsigned)l[6] | ((unsigned)l[7] << 16);
        *(uint2*)&Ah[ar * 40 + ak]     = p0;
        *(uint2*)&Ah[ar * 40 + ak + 4] = p1;
        *(uint2*)&Al[ar * 40 + ak]     = q0;
        *(uint2*)&Al[ar * 40 + ak + 4] = q1;
        *(bf16x8*)&Wh[wr * 40 + wk]     = wh0;
        *(bf16x8*)&Wh[wr * 40 + wk + 8] = wh1;
        *(bf16x8*)&Wl[wr * 40 + wk]     = wl0;
        *(bf16x8*)&Wl[wr * 40 + wk + 8] = wl1;
        __syncthreads();
        bf16x8 fAh = *(const bf16x8*)&Ah[(wave * 16 + frow) * 40 + fko];
        bf16x8 fAl = *(const bf16x8*)&Al[(wave * 16 + frow) * 40 + fko];
#pragma unroll
        for (int nt = 0; nt < 8; ++nt) {
            bf16x8 fWh = *(const bf16x8*)&Wh[(nt * 16 + frow) * 40 + fko];
            bf16x8 fWl = *(const bf16x8*)&Wl[(nt * 16 + frow) * 40 + fko];
            acc[nt] = __builtin_amdgcn_mfma_f32_16x16x32_bf16(fAh, fWh, acc[nt], 0, 0, 0);
            acc[nt] = __builtin_amdgcn_mfma_f32_16x16x32_bf16(fAh, fWl, acc[nt], 0, 0, 0);
            acc[nt] = __builtin_amdgcn_mfma_f32_16x16x32_bf16(fAl, fWh, acc[nt], 0, 0, 0);
        }
    }
    const int rbase = (lane >> 4) * 4;
#pragma unroll
    for (int nt = 0; nt < 8; ++nt) {
        const int col = nt * 16 + frow;
        const float bv = bia[col] + bib[col];
#pragma unroll
        for (int r = 0; r < 4; r++)
            out[(m0 + wave * 16 + rbase + r) * HH + col] = acc[nt][r] + bv;
    }
}

// ---------------------------------------------------------------------------
// Scan layer 1 FUSED with pre2, ROLE-SPLIT across 8 waves (512 thr/block):
//   waves 0-3 ("scan"): R1's proven 4-wave scan; lane holds Wr[32] = W_hh
//     slice only (32 VGPRs live across the barrier -- the regime the
//     allocator keeps in registers; R3/R5's 64-live version got remat'ed).
//   waves 4-7 ("gemm"): lane holds Wr[32] = W_ih2 slice; at iteration t they
//     compute pre2[b][t-1][j] = h_{t-1} . W_ih2[j] + b from hs[rb] (h_{t-1}),
//     one step behind the scan; drain step after the loop covers t = TT-1.
// Both roles read hs[rb] concurrently (reads only); scan writes hs[wb].
// One __syncthreads per step for all 8 waves.
// ---------------------------------------------------------------------------
__global__ __launch_bounds__(512) void rnn_scan8_fused1(
    const float* __restrict__ pre,   // [64][512][128] pre-activations layer 1
    const float* __restrict__ Whh,   // [128][128] fp32
    const float* __restrict__ Wih2,  // [128][128] fp32
    const float* __restrict__ bi2, const float* __restrict__ bh2,
    float* __restrict__ pre2)        // [64][512][128] out
{
    __shared__ __align__(16) _Float16 hs[2][HH];   // double buffer, 512 B
    const int tid  = threadIdx.x;
    const int wave = tid >> 6, lane = tid & 63;
    const int is_scan = (wave < 4);
    const int j  = (wave & 3) * 32 + (lane & 31);  // output unit 0..127
    const int kh = lane >> 5;                      // K half 0/1
    const int b  = blockIdx.x;

    h2f Wr[32];   // W_hh slice (scan waves) or W_ih2 slice (gemm waves)
    load_w32(Wr, (is_scan ? Whh : Wih2) + (size_t)j * HH + kh * 64);
    float bias2 = 0.f;
    if (!is_scan) bias2 = bi2[j] + bh2[j];
    if (tid < HH) hs[0][tid] = (_Float16)0.f;

    const float* pb = pre + (size_t)b * TT * HH;
    float* p2b = pre2 + (size_t)b * TT * HH;
    float pn0 = 0.f, pn1 = 0.f;
    if (is_scan) {                    // 2-deep prefetch of pre
        pn0 = pb[j];
        pn1 = pb[(size_t)HH + j];
    }
    __syncthreads();

    for (int t = 0; t < TT; ++t) {
        const int rb = t & 1;         // hs[rb] holds h_{t-1}
        const int wb = rb ^ 1;        // scan writes h_t here
        if (is_scan) {
            const float p = pn0;
            pn0 = pn1;
            if (t + 2 < TT) pn1 = pb[(size_t)(t + 2) * HH + j];
            float s = dot64_f16(Wr, &hs[rb][kh * 64]);
            s += __shfl_xor(s, 32);   // combine the two K-halves
            const float h = tanh_fast(p + s);
            if (lane < 32) hs[wb][j] = (_Float16)h;
        } else if (t > 0) {
            float s2 = dot64_f16(Wr, &hs[rb][kh * 64]);   // h_{t-1}
            s2 += __shfl_xor(s2, 32);
            if (lane < 32) p2b[(size_t)(t - 1) * HH + j] = s2 + bias2;
        }
        __syncthreads();              // publish h_t; all 8 waves
    }
    if (!is_scan) {                   // drain: pre2[TT-1] from h_{TT-1}
        float s2 = dot64_f16(Wr, &hs[TT & 1][kh * 64]);
        s2 += __shfl_xor(s2, 32);
        if (lane < 32) p2b[(size_t)(TT - 1) * HH + j] = s2 + bias2;
    }
}

// ---------------------------------------------------------------------------
// Scan layer 2 + FC head: R1's proven 4-wave structure + keep-alive asm.
// ---------------------------------------------------------------------------
__global__ __launch_bounds__(256) void rnn_scan4_final(
    const float* __restrict__ pre,   // [64][512][128] pre-activations layer 2
    const float* __restrict__ Whh,   // [128][128] fp32
    const float* __restrict__ Wfc, const float* __restrict__ bfc,
    float* __restrict__ outv)        // [64]
{
    __shared__ __align__(16) _Float16 hs[2][HH];
    __shared__ float red[4];
    const int tid  = threadIdx.x;
    const int wave = tid >> 6, lane = tid & 63;
    const int j  = wave * 32 + (lane & 31);
    const int kh = lane >> 5;
    const int b  = blockIdx.x;

    h2f Wr[32];
    load_w32(Wr, Whh + (size_t)j * HH + kh * 64);
    if (tid < HH) hs[0][tid] = (_Float16)0.f;

    const float* pb = pre + (size_t)b * TT * HH;
    float pn0 = pb[j];
    float pn1 = pb[(size_t)HH + j];
    float fcv = 0.f;
    __syncthreads();

    for (int t = 0; t < TT; ++t) {
        const float p = pn0;
        pn0 = pn1;
        if (t + 2 < TT) pn1 = pb[(size_t)(t + 2) * HH + j];
        const int rb = t & 1;
        const int wb = rb ^ 1;
        float s = dot64_f16(Wr, &hs[rb][kh * 64]);
        s += __shfl_xor(s, 32);
        const float h = tanh_fast(p + s);
        if (lane < 32) hs[wb][j] = (_Float16)h;
        if (t == TT - 1 && lane < 32) fcv = h * Wfc[j];
        __syncthreads();
    }

#pragma unroll
    for (int off = 1; off < 64; off <<= 1) fcv += __shfl_xor(fcv, off);
    if (lane == 0) red[wave] = fcv;
    __syncthreads();
    if (tid == 0) outv[b] = red[0] + red[1] + red[2] + red[3] + bfc[0];
}

// ---------------------------------------------------------------------------
extern "C" void kernel_launch(void* const* d_in, const int* in_sizes, int n_in,
                              void* d_out, int out_size, void* d_ws, size_t ws_size,
                              hipStream_t stream) {
    const float* x    = (const float*)d_in[0];
    const float* Wih1 = (const float*)d_in[1];
    const float* Whh1 = (const float*)d_in[2];
    const float* bih1 = (const float*)d_in[3];
    const float* bhh1 = (const float*)d_in[4];
    const float* Wih2 = (const float*)d_in[5];
    const float* Whh2 = (const float*)d_in[6];
    const float* bih2 = (const float*)d_in[7];
    const float* bhh2 = (const float*)d_in[8];
    const float* Wfc  = (const float*)d_in[9];
    const float* bfc  = (const float*)d_in[10];
    float* out = (float*)d_out;

    float* preA = (float*)d_ws;                    // 16 MB  (pre1)
    float* preB = preA + (size_t)M1 * HH;          // 16 MB  (pre2)
    // Whi/Wlo alias the head of preB: consumed by gemm1 BEFORE scan1 writes preB
    unsigned short* Whi = (unsigned short*)preB;
    unsigned short* Wlo = Whi + (size_t)HH * DD;

    prep_w_kernel<<<dim3(HH * DD / 1024), dim3(256), 0, stream>>>(Wih1, Whi, Wlo);
    gemm1_mfma_kernel<<<dim3(M1 / 64), dim3(256), 0, stream>>>(x, Whi, Wlo, bih1, bhh1, preA);
    rnn_scan8_fused1<<<dim3(BB), dim3(512), 0, stream>>>(
        preA, Whh1, Wih2, bih2, bhh2, preB);
    rnn_scan4_final<<<dim3(BB), dim3(256), 0, stream>>>(
        preB, Whh2, Wfc, bfc, out);
}